// Round 17
// baseline (101.531 us; speedup 1.0000x reference)
//
#include <hip/hip_runtime.h>
#include <hip/hip_bf16.h>
#include <math.h>

#define T_LEN 2048
#define BATCH 4
#define DMODEL 256
#define MROWS (BATCH*T_LEN)
#define PLANE (MROWS*DMODEL)
#define CH_L 32
#define NCH  (T_LEN/CH_L)          // 64
#define SUMSZ (BATCH*NCH*DMODEL)   // 65536
#define MSLOT (DMODEL*DMODEL)      // 65536

typedef __bf16 bf16;
typedef __bf16 bf16x4 __attribute__((ext_vector_type(4)));
typedef __bf16 bf16x8 __attribute__((ext_vector_type(8)));
typedef _Float16 f16;
typedef _Float16 f16x8 __attribute__((ext_vector_type(8)));
typedef float  f32x4  __attribute__((ext_vector_type(4)));
typedef unsigned short u16;
typedef u16 u16x8 __attribute__((ext_vector_type(8)));
typedef unsigned int u32;

#define MFMA(a,b,c)   __builtin_amdgcn_mfma_f32_16x16x32_bf16(a, b, c, 0, 0, 0)
#define MFMA16(a,b,c) __builtin_amdgcn_mfma_f32_16x16x32_f16(a, b, c, 0, 0, 0)

__device__ __forceinline__ void split_bf16(float x, bf16& hi, bf16& lo) {
    hi = (bf16)x;
    lo = (bf16)(x - (float)hi);
}

// fast transcendentals (hardware v_exp_f32 based)
__device__ __forceinline__ float tanh_fast(float z) {
    z = fminf(fmaxf(z, -15.f), 15.f);
    float e = __expf(2.f * z);
    return (e - 1.f) / (e + 1.f);
}
__device__ __forceinline__ float nsoftplus_fast(float y) {   // -softplus(y)
    return -(fmaxf(y, 0.f) + __logf(1.f + __expf(-fabsf(y))));
}
__device__ __forceinline__ float sigmoid_fast(float y) {
    return 1.f / (1.f + __expf(-y));
}

#define GLD16(SRC, DST) __builtin_amdgcn_global_load_lds( \
    (const __attribute__((address_space(1))) void*)(SRC), \
    (__attribute__((address_space(3))) void*)(DST), 16, 0, 0)

// ---------------- merged prep: blocks [0,1024) convert x->f16; blocks [1024,1120) pack W
__global__ __launch_bounds__(256) void prep(const float* __restrict__ x,
                                            const float* __restrict__ Wq,
                                            const float* __restrict__ Wk,
                                            const float* __restrict__ Wv,
                                            const float* __restrict__ Wg,
                                            const float* __restrict__ bq,
                                            const float* __restrict__ bk,
                                            const float* __restrict__ bv,
                                            const float* __restrict__ bg,
                                            const float* __restrict__ input_bias,
                                            f16* __restrict__ xf,
                                            f16* __restrict__ Wf,
                                            float* __restrict__ biasC) {
    __shared__ float tile[16][260];
    const int tid = threadIdx.x;
    if (blockIdx.x < 1024) {
        int i = (blockIdx.x*256 + tid) * 8;
        f32x4 a = *(const f32x4*)(x + i);
        f32x4 b = *(const f32x4*)(x + i + 4);
        f16x8 h;
        #pragma unroll
        for (int e = 0; e < 4; ++e) {
            h[e]   = (f16)a[e];
            h[4+e] = (f16)b[e];
        }
        *(f16x8*)(xf + i) = h;
        return;
    }
    const int n0 = (blockIdx.x - 1024) * 16;
    const float* src; int nb, nw;
    float scale = 1.0f;
    if (n0 < 256)      { src = Wq; nb = n0;       nw = 256; }
    else if (n0 < 512) { src = Wk; nb = n0 - 256; nw = 256; scale = 0.0625f; }
    else if (n0 < 768) { src = Wv; nb = n0 - 512; nw = 256; }
    else               { src = Wg; nb = n0 - 768; nw = 768; }
    const int j = tid & 15, kk = tid >> 4;
    #pragma unroll
    for (int r = 0; r < 16; ++r) {
        int k = r*16 + kk;
        tile[j][k] = src[(size_t)k*nw + nb + j] * scale;
    }
    __syncthreads();
    #pragma unroll
    for (int r = 0; r < 16; ++r)
        Wf[(size_t)(n0 + r)*256 + tid] = (f16)tile[r][tid];
    if (tid < 16) {
        int n = n0 + tid;
        float bC;
        if (n < 256)        bC = bq[n];
        else if (n < 512)   bC = bk[n-256] * 0.0625f;
        else if (n < 768)   bC = bv[n-512];
        else if (n < 1024)  bC = bg[n-768] + input_bias[n-768];
        else                bC = bg[n-768];
        biasC[n] = bC;
    }
}

// ---------------- fused projection GEMM: f16, BK=64, grid (12 n-tiles, 64 m-tiles)
// so consecutive blocks share the A-panel across XCDs (L2 reuse).
__global__ __launch_bounds__(256, 4) void proj_gemm(
    const f16* __restrict__ xf, const f16* __restrict__ Wf,
    const float* __restrict__ biasC,
    f16* __restrict__ qP, f16* __restrict__ kP, f16* __restrict__ vP,
    f16* __restrict__ liP, f16* __restrict__ lfP, f16* __restrict__ soP)
{
    __shared__ f16 Af[128*64];
    __shared__ f16 Bf[128*64];
    const int tid = threadIdx.x;
    const int w = tid >> 6, l = tid & 63;
    const int wr = w >> 1, wc = w & 1;
    const int m0 = blockIdx.y * 128;     // row tile (64)
    const int n0 = blockIdx.x * 128;     // col tile (12)
    const int lr = l & 15, lk = l >> 4;

    f32x4 acc[4][4] = {};

    for (int kt = 0; kt < 256; kt += 64) {
        #pragma unroll
        for (int p = 0; p < 4; ++p) {
            int e = p*2048 + tid*8;
            int row = e >> 6;
            int slot = (e >> 3) & 7;
            int scol = ((slot ^ (row & 7)) << 3);
            GLD16(xf + (size_t)(m0 + row)*256 + kt + scol, Af + e);
            GLD16(Wf + (size_t)(n0 + row)*256 + kt + scol, Bf + e);
        }
        __syncthreads();

        #pragma unroll
        for (int ksub = 0; ksub < 2; ++ksub) {
            f16x8 af[4], bf[4];
            #pragma unroll
            for (int mi = 0; mi < 4; ++mi) {
                int row = wr*64 + mi*16 + lr;
                int slot = (ksub*4 + lk) ^ (row & 7);
                af[mi] = *(const f16x8*)(Af + row*64 + slot*8);
            }
            #pragma unroll
            for (int ni = 0; ni < 4; ++ni) {
                int row = wc*64 + ni*16 + lr;
                int slot = (ksub*4 + lk) ^ (row & 7);
                bf[ni] = *(const f16x8*)(Bf + row*64 + slot*8);
            }
            #pragma unroll
            for (int ni = 0; ni < 4; ++ni)
                #pragma unroll
                for (int mi = 0; mi < 4; ++mi)
                    acc[mi][ni] = MFMA16(af[mi], bf[ni], acc[mi][ni]);
        }
        __syncthreads();
    }

    const int seg = n0 >> 8;   // wg-uniform plane select
    f16* dst = (seg == 0) ? qP : (seg == 1) ? kP : (seg == 2) ? vP
             : (seg == 3) ? liP : (seg == 4) ? lfP : soP;
    #pragma unroll
    for (int mi = 0; mi < 4; ++mi) {
        #pragma unroll
        for (int ni = 0; ni < 4; ++ni) {
            int gcol = n0 + wc*64 + ni*16 + lr;
            int c = gcol & 255;
            float bC = biasC[gcol];
            #pragma unroll
            for (int r = 0; r < 4; ++r) {
                int grow = m0 + wr*64 + mi*16 + lk*4 + r;
                dst[(size_t)grow*256 + c] = (f16)(acc[mi][ni][r] + bC);
            }
        }
    }
}

// ---------------- fused chunk summary + Delta-M (bf16 split staging, bf16 DM):
__global__ __launch_bounds__(256) void s2_dm(
    const f16* __restrict__ kP, const f16* __restrict__ vP,
    const f16* __restrict__ liP, const f16* __restrict__ lfP,
    float* __restrict__ Csum, float* __restrict__ Mu, float* __restrict__ Bn,
    bf16* __restrict__ DM)
{
    __shared__ bf16 BTh[DMODEL][40], BTl[DMODEL][40];
    __shared__ bf16 KTh[DMODEL][40], KTl[DMODEL][40];
    const int tid = threadIdx.x;
    const int w = tid >> 6, l = tid & 63;
    const int b = blockIdx.x >> 6, c = blockIdx.x & 63;
    const size_t pb = ((size_t)b*T_LEN + (size_t)c*CH_L)*DMODEL;

    {
        float C = 0.f, mu = -3e38f;
        float val[CH_L];
        #pragma unroll
        for (int s = 0; s < CH_L; ++s) {
            size_t o = pb + (size_t)s*DMODEL + tid;
            C += nsoftplus_fast((float)lfP[o]);
            val[s] = 10.0f * tanh_fast(0.1f * (float)liP[o]) - C;
            mu = fmaxf(mu, val[s]);
        }
        float bn = 0.f;
        #pragma unroll
        for (int s = 0; s < CH_L; ++s) {
            size_t o = pb + (size_t)s*DMODEL + tid;
            float e = __expf(val[s] - mu);
            float kv = (float)kP[o];
            bn += e * kv;
            float bv = e * (float)vP[o];
            bf16 h, lo; split_bf16(bv, h, lo);
            BTh[tid][s] = h; BTl[tid][s] = lo;
            bf16 kh, kl; split_bf16(kv, kh, kl);
            KTh[tid][s] = kh; KTl[tid][s] = kl;
        }
        size_t so = ((size_t)b*NCH + c)*DMODEL + tid;
        Csum[so] = C; Mu[so] = mu; Bn[so] = bn;
    }
    __syncthreads();

    const int lr = l & 15, lk = l >> 4;
    bf16x8 Ah[4], Al[4];
    #pragma unroll
    for (int it = 0; it < 4; ++it) {
        int row = w*64 + it*16 + lr;
        Ah[it] = *(const bf16x8*)&BTh[row][lk*8];
        Al[it] = *(const bf16x8*)&BTl[row][lk*8];
    }
    bf16* DMc = DM + (size_t)((size_t)b*NCH + c)*MSLOT;
    #pragma unroll
    for (int jt = 0; jt < 16; ++jt) {
        int jcol = jt*16 + lr;
        bf16x8 bh = *(const bf16x8*)&KTh[jcol][lk*8];
        bf16x8 bl = *(const bf16x8*)&KTl[jcol][lk*8];
        #pragma unroll
        for (int it = 0; it < 4; ++it) {
            f32x4 a = {0.f,0.f,0.f,0.f};
            a = MFMA(Ah[it], bh, a);
            a = MFMA(Al[it], bh, a);
            a = MFMA(Ah[it], bl, a);
            #pragma unroll
            for (int r = 0; r < 4; ++r)
                DMc[(size_t)(w*64 + it*16 + lk*4 + r)*DMODEL + jcol] = (bf16)a[r];
        }
    }
}

// ---------------- sequential compose of (m,n) boundary states (batch-4 prefetched)
__global__ __launch_bounds__(256) void chunk_compose(
    const float* __restrict__ Csum, const float* __restrict__ Mu, const float* __restrict__ Bn,
    float* __restrict__ mIn, float* __restrict__ nIn, float* __restrict__ Th,
    float* __restrict__ Dd, float* __restrict__ Ee)
{
    const int b = blockIdx.x;
    const int j = threadIdx.x;
    float m = 0.f, n = 0.f;
    #pragma unroll 1
    for (int c = 0; c < NCH; c += 4) {
        size_t o0 = ((size_t)b*NCH + c)*DMODEL + j;
        float cs0 = Csum[o0],            mu0 = Mu[o0],            bn0 = Bn[o0];
        float cs1 = Csum[o0 + DMODEL],   mu1 = Mu[o0 + DMODEL],   bn1 = Bn[o0 + DMODEL];
        float cs2 = Csum[o0 + 2*DMODEL], mu2 = Mu[o0 + 2*DMODEL], bn2 = Bn[o0 + 2*DMODEL];
        float cs3 = Csum[o0 + 3*DMODEL], mu3 = Mu[o0 + 3*DMODEL], bn3 = Bn[o0 + 3*DMODEL];
        #define STEP(CS, MUv, BNv, OFF) { \
            mIn[o0 + (OFF)] = m; nIn[o0 + (OFF)] = n; \
            float th = fmaxf(m, MUv); \
            Th[o0 + (OFF)] = th; \
            float emu = __expf(MUv - th); \
            float d = __expf(m - th); \
            Dd[o0 + (OFF)] = d; Ee[o0 + (OFF)] = emu; \
            n = d*n + emu*(BNv); \
            m = (CS) + th; }
        STEP(cs0, mu0, bn0, 0)
        STEP(cs1, mu1, bn1, DMODEL)
        STEP(cs2, mu2, bn2, 2*DMODEL)
        STEP(cs3, mu3, bn3, 3*DMODEL)
        #undef STEP
    }
}

// ---------------- compose M across chunks; 1024 blocks x 256 threads (1 i-row each,
// 4 blocks/CU for latency hiding of the 128KB-strided chain)
__global__ __launch_bounds__(256) void s3_compose(
    const float* __restrict__ Dd, const float* __restrict__ Ee, bf16* __restrict__ DM)
{
    const int b = blockIdx.x >> 8;
    const int i = blockIdx.x & 255;
    const int j = threadIdx.x;
    float acc = 0.f;
    const size_t base = ((size_t)b*NCH)*MSLOT + (size_t)i*DMODEL + j;
    const size_t sb = (size_t)b*NCH*DMODEL + i;
    #pragma unroll 1
    for (int c = 0; c < NCH; c += 4) {
        float dm0 = (float)DM[base + (size_t)(c+0)*MSLOT];
        float dm1 = (float)DM[base + (size_t)(c+1)*MSLOT];
        float dm2 = (float)DM[base + (size_t)(c+2)*MSLOT];
        float dm3 = (float)DM[base + (size_t)(c+3)*MSLOT];
        float d0 = Dd[sb + (size_t)(c+0)*DMODEL], e0 = Ee[sb + (size_t)(c+0)*DMODEL];
        float d1 = Dd[sb + (size_t)(c+1)*DMODEL], e1 = Ee[sb + (size_t)(c+1)*DMODEL];
        float d2 = Dd[sb + (size_t)(c+2)*DMODEL], e2 = Ee[sb + (size_t)(c+2)*DMODEL];
        float d3 = Dd[sb + (size_t)(c+3)*DMODEL], e3 = Ee[sb + (size_t)(c+3)*DMODEL];
        if (c > 0) DM[base + (size_t)(c+0)*MSLOT] = (bf16)acc;
        acc = d0*acc + e0*dm0;
        DM[base + (size_t)(c+1)*MSLOT] = (bf16)acc;
        acc = d1*acc + e1*dm1;
        DM[base + (size_t)(c+2)*MSLOT] = (bf16)acc;
        acc = d2*acc + e2*dm2;
        DM[base + (size_t)(c+3)*MSLOT] = (bf16)acc;
        acc = d3*acc + e3*dm3;
    }
}

// ---------------- per-chunk output + fused RMSNorm (bf16 MFMA path, f16 plane inputs)
__global__ __launch_bounds__(256) void s4_chunk(
    const f16* __restrict__ qP, const f16* __restrict__ kP, const f16* __restrict__ vP,
    const f16* __restrict__ liP, const f16* __restrict__ lfP, const f16* __restrict__ soP,
    const float* __restrict__ mIn, const float* __restrict__ nIn, const float* __restrict__ Th,
    const bf16* __restrict__ DM, const float* __restrict__ norm_scale,
    float* __restrict__ out)
{
    __shared__ __align__(16) char kqbuf[33792];
    bf16 (*Kf)[264] = (bf16(*)[264])kqbuf;
    bf16 (*Qf)[264] = (bf16(*)[264])(kqbuf + 16896);
    float (*Hout)[264] = (float(*)[264])kqbuf;
    __shared__ bf16 F1L[CH_L][264];
    __shared__ __align__(16) bf16 BTh[DMODEL][40];
    __shared__ __align__(16) bf16 GT[CH_L][48];
    __shared__ float part[CH_L][4];
    __shared__ float denoms[CH_L];
    __shared__ float exL[DMODEL];

    const int tid = threadIdx.x;
    const int w = tid >> 6, l = tid & 63;
    const int b = blockIdx.x >> 6;
    const int c = blockIdx.x & 63;
    const size_t pb = ((size_t)b*T_LEN + (size_t)c*CH_L)*DMODEL;

    // phase 1: per-dim recurrences (thread = dim)
    const int i = tid;
    const size_t cbx = ((size_t)b*NCH + c)*DMODEL + i;
    const float thL = Th[cbx];
    const float mI = mIn[cbx];
    float P[CH_L];
    {
        float C = 0.f, mu = -3e38f, n = nIn[cbx], thp = mI;
        #pragma unroll
        for (int t = 0; t < CH_L; ++t) {
            size_t o = pb + (size_t)t*DMODEL + i;
            float lf = nsoftplus_fast((float)lfP[o]);
            float li = 10.0f * tanh_fast(0.1f * (float)liP[o]);
            float kv = (float)kP[o], qv = (float)qP[o], vv = (float)vP[o];
            C += lf;
            float vlc = li - C;
            mu = fmaxf(mu, vlc);
            float tht = fmaxf(mI, mu);
            float f = __expf(thp - tht);
            float iv = __expf(vlc - tht);
            n = f*n + iv*kv;
            thp = tht;
            P[t] = n * qv;
            Kf[t][i] = (bf16)kv;
            Qf[t][i] = (bf16)qv;
            F1L[t][i] = (bf16)__expf(mI - tht);
            BTh[i][t] = (bf16)(__expf(vlc - thL) * vv);
        }
        exL[i] = __expf(thL - mI);
    }
    // phase 2: wave-reduce P
    #pragma unroll
    for (int t = 0; t < CH_L; ++t) {
        float s = P[t];
        #pragma unroll
        for (int sh = 32; sh; sh >>= 1) s += __shfl_xor(s, sh);
        if (l == 0) part[t][w] = s;
    }
    __syncthreads();

    // phase 3a: denominators
    if (tid < CH_L)
        denoms[tid] = fmaxf(fabsf(part[tid][0] + part[tid][1] + part[tid][2] + part[tid][3]), 1e-6f);

    // phase 3b: G = K Q^T single-pass bf16
    {
        const int a = w & 1, bb = w >> 1;
        const int lr = l & 15, lk2 = l >> 4;
        if (a == 1 && bb == 0) {
            bf16x4 z = {(bf16)0.f, (bf16)0.f, (bf16)0.f, (bf16)0.f};
            *(bf16x4*)&GT[lr][16 + lk2*4] = z;
        } else {
            f32x4 g = {0.f,0.f,0.f,0.f};
            #pragma unroll
            for (int ks = 0; ks < 8; ++ks) {
                bf16x8 ah = *(const bf16x8*)&Kf[16*a  + lr][ks*32 + lk2*8];
                bf16x8 bh = *(const bf16x8*)&Qf[16*bb + lr][ks*32 + lk2*8];
                g = MFMA(ah, bh, g);
            }
            bf16x4 gv;
            #pragma unroll
            for (int r = 0; r < 4; ++r) {
                int s = 16*a + lk2*4 + r, t = 16*bb + lr;
                gv[r] = (s <= t) ? (bf16)g[r] : (bf16)0.f;
            }
            *(bf16x4*)&GT[16*bb + lr][16*a + lk2*4] = gv;
        }
    }
    __syncthreads();

    // phase 4: output GEMMs
    const int tt = w & 1;
    const int lr = l & 15, lk2 = l >> 4;
    const int trow = tt*16 + lr;
    f32x4 acc_a[8], acc_b[8];

    {
        bf16x8 gh = *(const bf16x8*)&GT[trow][lk2*8];
        #pragma unroll
        for (int it = 0; it < 8; ++it) {
            int irow = ((w>>1)*8 + it)*16 + lr;
            bf16x8 bb2 = *(const bf16x8*)&BTh[irow][lk2*8];
            f32x4 a = {0.f,0.f,0.f,0.f};
            acc_a[it] = MFMA(gh, bb2, a);
        }
    }
    #pragma unroll
    for (int it = 0; it < 8; ++it) acc_b[it] = (f32x4){0.f,0.f,0.f,0.f};
    if (c > 0) {
        const u16* Mbase = (const u16*)DM + (size_t)((size_t)b*NCH + c)*MSLOT;
        #pragma unroll
        for (int ks = 0; ks < 8; ++ks) {
            bf16x8 qh = *(const bf16x8*)&Qf[trow][ks*32 + lk2*8];
            #pragma unroll
            for (int it = 0; it < 8; ++it) {
                int irow = ((w>>1)*8 + it)*16 + lr;
                union { u16x8 u; bf16x8 h; } M8;
                M8.u = *(const u16x8*)(Mbase + (size_t)irow*DMODEL + ks*32 + lk2*8);
                acc_b[it] = MFMA(qh, M8.h, acc_b[it]);
            }
        }
    }
    __syncthreads();   // all Kf/Qf reads done; kqbuf becomes Hout

    // epilogue part 1
    #pragma unroll
    for (int it = 0; it < 8; ++it) {
        int icol = ((w>>1)*8 + it)*16 + lr;
        float ex = exL[icol];
        #pragma unroll
        for (int r = 0; r < 4; ++r) {
            int t = tt*16 + lk2*4 + r;
            float F1 = (float)F1L[t][icol];
            float h = F1 * (acc_b[it][r] + ex * acc_a[it][r]);
            size_t o = pb + (size_t)t*DMODEL + icol;
            Hout[t][icol] = sigmoid_fast((float)soP[o]) * h / denoms[t];
        }
    }
    __syncthreads();
    // epilogue part 2: fused RMSNorm
    #pragma unroll
    for (int r = 0; r < 8; ++r) {
        int t = w*8 + r;
        f32x4 hv = *(const f32x4*)&Hout[t][l*4];
        float ss = hv[0]*hv[0] + hv[1]*hv[1] + hv[2]*hv[2] + hv[3]*hv[3];
        #pragma unroll
        for (int sh = 32; sh; sh >>= 1) ss += __shfl_xor(ss, sh);
        float rinv = rsqrtf(ss * (1.0f/256.0f) + 1e-8f);
        f32x4 ns = *(const f32x4*)(norm_scale + l*4);
        f32x4 o4;
        #pragma unroll
        for (int e = 0; e < 4; ++e) o4[e] = hv[e] * rinv * ns[e];
        *(f32x4*)(out + pb + (size_t)t*DMODEL + l*4) = o4;
    }
}

extern "C" void kernel_launch(void* const* d_in, const int* in_sizes, int n_in,
                              void* d_out, int out_size, void* d_ws, size_t ws_size,
                              hipStream_t stream) {
    const float* x          = (const float*)d_in[0];
    const float* Wq         = (const float*)d_in[1];
    const float* bq         = (const float*)d_in[2];
    const float* Wk         = (const float*)d_in[3];
    const float* bk         = (const float*)d_in[4];
    const float* Wv         = (const float*)d_in[5];
    const float* bv         = (const float*)d_in[6];
    const float* Wg         = (const float*)d_in[7];
    const float* bg         = (const float*)d_in[8];
    const float* input_bias = (const float*)d_in[9];
    const float* norm_scale = (const float*)d_in[10];
    float* out = (float*)d_out;

    // f32 scratch
    float* Csum = (float*)d_ws;
    float* Mu   = Csum + SUMSZ;
    float* Bn   = Mu   + SUMSZ;
    float* mIn  = Bn   + SUMSZ;
    float* nIn  = mIn  + SUMSZ;
    float* Th   = nIn  + SUMSZ;
    float* Dd   = Th   + SUMSZ;
    float* Ee   = Dd   + SUMSZ;
    float* biasC = Ee  + SUMSZ;                        // 1536 floats (pad 2048)
    // f16/bf16 scratch
    f16*   qP   = (f16*)(biasC + 2048);
    f16*   kP   = qP  + PLANE;
    f16*   vP   = kP  + PLANE;
    f16*   liP  = vP  + PLANE;
    f16*   lfP  = liP + PLANE;
    f16*   soP  = lfP + PLANE;
    bf16*  DM   = (bf16*)(soP + PLANE);                // 4*64*65536 bf16 = 32 MiB
    f16*   Wf   = (f16*)(DM + (size_t)BATCH*NCH*MSLOT);
    f16*   xf   = Wf + 1536*256;

    prep<<<dim3(1120), dim3(256), 0, stream>>>(x, Wq, Wk, Wv, Wg, bq, bk, bv, bg, input_bias,
                                               xf, Wf, biasC);
    proj_gemm<<<dim3(12, 64), dim3(256), 0, stream>>>(xf, Wf, biasC,
                                                      qP, kP, vP, liP, lfP, soP);
    s2_dm<<<dim3(BATCH*NCH), dim3(256), 0, stream>>>(kP, vP, liP, lfP, Csum, Mu, Bn, DM);
    chunk_compose<<<dim3(BATCH), dim3(256), 0, stream>>>(Csum, Mu, Bn, mIn, nIn, Th, Dd, Ee);
    s3_compose<<<dim3(BATCH*256), dim3(256), 0, stream>>>(Dd, Ee, DM);
    s4_chunk<<<dim3(BATCH*NCH), dim3(256), 0, stream>>>(qP, kP, vP, liP, lfP, soP,
                                                        mIn, nIn, Th, DM, norm_scale, out);
}

// Round 18
// 92.345 us; speedup vs baseline: 1.0995x; 1.0995x over previous
//
#include <hip/hip_runtime.h>
#include <hip/hip_bf16.h>
#include <math.h>

#define T_LEN 2048
#define BATCH 4
#define DMODEL 256
#define MROWS (BATCH*T_LEN)
#define PLANE (MROWS*DMODEL)
#define CH_L 32
#define NCH  (T_LEN/CH_L)          // 64
#define SUMSZ (BATCH*NCH*DMODEL)   // 65536
#define MSLOT (DMODEL*DMODEL)      // 65536

typedef __bf16 bf16;
typedef __bf16 bf16x4 __attribute__((ext_vector_type(4)));
typedef __bf16 bf16x8 __attribute__((ext_vector_type(8)));
typedef _Float16 f16;
typedef _Float16 f16x8 __attribute__((ext_vector_type(8)));
typedef float  f32x4  __attribute__((ext_vector_type(4)));
typedef unsigned short u16;
typedef u16 u16x8 __attribute__((ext_vector_type(8)));
typedef unsigned int u32;

#define MFMA(a,b,c)   __builtin_amdgcn_mfma_f32_16x16x32_bf16(a, b, c, 0, 0, 0)
#define MFMA16(a,b,c) __builtin_amdgcn_mfma_f32_16x16x32_f16(a, b, c, 0, 0, 0)

__device__ __forceinline__ void split_bf16(float x, bf16& hi, bf16& lo) {
    hi = (bf16)x;
    lo = (bf16)(x - (float)hi);
}

// fast transcendentals (hardware v_exp_f32 based)
__device__ __forceinline__ float tanh_fast(float z) {
    z = fminf(fmaxf(z, -15.f), 15.f);
    float e = __expf(2.f * z);
    return (e - 1.f) / (e + 1.f);
}
__device__ __forceinline__ float nsoftplus_fast(float y) {   // -softplus(y)
    return -(fmaxf(y, 0.f) + __logf(1.f + __expf(-fabsf(y))));
}
__device__ __forceinline__ float sigmoid_fast(float y) {
    return 1.f / (1.f + __expf(-y));
}

#define GLD16(SRC, DST) __builtin_amdgcn_global_load_lds( \
    (const __attribute__((address_space(1))) void*)(SRC), \
    (__attribute__((address_space(3))) void*)(DST), 16, 0, 0)

// ---------------- merged prep: blocks [0,1024) convert x->f16; blocks [1024,1120) pack W
__global__ __launch_bounds__(256) void prep(const float* __restrict__ x,
                                            const float* __restrict__ Wq,
                                            const float* __restrict__ Wk,
                                            const float* __restrict__ Wv,
                                            const float* __restrict__ Wg,
                                            const float* __restrict__ bq,
                                            const float* __restrict__ bk,
                                            const float* __restrict__ bv,
                                            const float* __restrict__ bg,
                                            const float* __restrict__ input_bias,
                                            f16* __restrict__ xf,
                                            f16* __restrict__ Wf,
                                            float* __restrict__ biasC) {
    __shared__ float tile[16][260];
    const int tid = threadIdx.x;
    if (blockIdx.x < 1024) {
        int i = (blockIdx.x*256 + tid) * 8;
        f32x4 a = *(const f32x4*)(x + i);
        f32x4 b = *(const f32x4*)(x + i + 4);
        f16x8 h;
        #pragma unroll
        for (int e = 0; e < 4; ++e) {
            h[e]   = (f16)a[e];
            h[4+e] = (f16)b[e];
        }
        *(f16x8*)(xf + i) = h;
        return;
    }
    const int n0 = (blockIdx.x - 1024) * 16;
    const float* src; int nb, nw;
    float scale = 1.0f;
    if (n0 < 256)      { src = Wq; nb = n0;       nw = 256; }
    else if (n0 < 512) { src = Wk; nb = n0 - 256; nw = 256; scale = 0.0625f; }
    else if (n0 < 768) { src = Wv; nb = n0 - 512; nw = 256; }
    else               { src = Wg; nb = n0 - 768; nw = 768; }
    const int j = tid & 15, kk = tid >> 4;
    #pragma unroll
    for (int r = 0; r < 16; ++r) {
        int k = r*16 + kk;
        tile[j][k] = src[(size_t)k*nw + nb + j] * scale;
    }
    __syncthreads();
    #pragma unroll
    for (int r = 0; r < 16; ++r)
        Wf[(size_t)(n0 + r)*256 + tid] = (f16)tile[r][tid];
    if (tid < 16) {
        int n = n0 + tid;
        float bC;
        if (n < 256)        bC = bq[n];
        else if (n < 512)   bC = bk[n-256] * 0.0625f;
        else if (n < 768)   bC = bv[n-512];
        else if (n < 1024)  bC = bg[n-768] + input_bias[n-768];
        else                bC = bg[n-768];
        biasC[n] = bC;
    }
}

// ---------------- fused projection GEMM: f16, BK=64 (half the barrier drains).
// 128x128 tile, 32KB LDS, 8-slot XOR swizzle both sides, uniform epilogue.
__global__ __launch_bounds__(256, 4) void proj_gemm(
    const f16* __restrict__ xf, const f16* __restrict__ Wf,
    const float* __restrict__ biasC,
    f16* __restrict__ qP, f16* __restrict__ kP, f16* __restrict__ vP,
    f16* __restrict__ liP, f16* __restrict__ lfP, f16* __restrict__ soP)
{
    __shared__ f16 Af[128*64];
    __shared__ f16 Bf[128*64];
    const int tid = threadIdx.x;
    const int w = tid >> 6, l = tid & 63;
    const int wr = w >> 1, wc = w & 1;
    const int m0 = blockIdx.x * 128;
    const int n0 = blockIdx.y * 128;
    const int lr = l & 15, lk = l >> 4;

    f32x4 acc[4][4] = {};

    for (int kt = 0; kt < 256; kt += 64) {
        #pragma unroll
        for (int p = 0; p < 4; ++p) {
            int e = p*2048 + tid*8;
            int row = e >> 6;
            int slot = (e >> 3) & 7;
            int scol = ((slot ^ (row & 7)) << 3);
            GLD16(xf + (size_t)(m0 + row)*256 + kt + scol, Af + e);
            GLD16(Wf + (size_t)(n0 + row)*256 + kt + scol, Bf + e);
        }
        __syncthreads();

        #pragma unroll
        for (int ksub = 0; ksub < 2; ++ksub) {
            f16x8 af[4], bf[4];
            #pragma unroll
            for (int mi = 0; mi < 4; ++mi) {
                int row = wr*64 + mi*16 + lr;
                int slot = (ksub*4 + lk) ^ (row & 7);
                af[mi] = *(const f16x8*)(Af + row*64 + slot*8);
            }
            #pragma unroll
            for (int ni = 0; ni < 4; ++ni) {
                int row = wc*64 + ni*16 + lr;
                int slot = (ksub*4 + lk) ^ (row & 7);
                bf[ni] = *(const f16x8*)(Bf + row*64 + slot*8);
            }
            #pragma unroll
            for (int ni = 0; ni < 4; ++ni)
                #pragma unroll
                for (int mi = 0; mi < 4; ++mi)
                    acc[mi][ni] = MFMA16(af[mi], bf[ni], acc[mi][ni]);
        }
        __syncthreads();
    }

    const int seg = n0 >> 8;   // wg-uniform plane select
    f16* dst = (seg == 0) ? qP : (seg == 1) ? kP : (seg == 2) ? vP
             : (seg == 3) ? liP : (seg == 4) ? lfP : soP;
    #pragma unroll
    for (int mi = 0; mi < 4; ++mi) {
        #pragma unroll
        for (int ni = 0; ni < 4; ++ni) {
            int gcol = n0 + wc*64 + ni*16 + lr;
            int c = gcol & 255;
            float bC = biasC[gcol];
            #pragma unroll
            for (int r = 0; r < 4; ++r) {
                int grow = m0 + wr*64 + mi*16 + lk*4 + r;
                dst[(size_t)grow*256 + c] = (f16)(acc[mi][ni][r] + bC);
            }
        }
    }
}

// ---------------- fused chunk summary + Delta-M (bf16 split staging, bf16 DM):
__global__ __launch_bounds__(256) void s2_dm(
    const f16* __restrict__ kP, const f16* __restrict__ vP,
    const f16* __restrict__ liP, const f16* __restrict__ lfP,
    float* __restrict__ Csum, float* __restrict__ Mu, float* __restrict__ Bn,
    bf16* __restrict__ DM)
{
    __shared__ bf16 BTh[DMODEL][40], BTl[DMODEL][40];
    __shared__ bf16 KTh[DMODEL][40], KTl[DMODEL][40];
    const int tid = threadIdx.x;
    const int w = tid >> 6, l = tid & 63;
    const int b = blockIdx.x >> 6, c = blockIdx.x & 63;
    const size_t pb = ((size_t)b*T_LEN + (size_t)c*CH_L)*DMODEL;

    {
        float C = 0.f, mu = -3e38f;
        float val[CH_L];
        #pragma unroll
        for (int s = 0; s < CH_L; ++s) {
            size_t o = pb + (size_t)s*DMODEL + tid;
            C += nsoftplus_fast((float)lfP[o]);
            val[s] = 10.0f * tanh_fast(0.1f * (float)liP[o]) - C;
            mu = fmaxf(mu, val[s]);
        }
        float bn = 0.f;
        #pragma unroll
        for (int s = 0; s < CH_L; ++s) {
            size_t o = pb + (size_t)s*DMODEL + tid;
            float e = __expf(val[s] - mu);
            float kv = (float)kP[o];
            bn += e * kv;
            float bv = e * (float)vP[o];
            bf16 h, lo; split_bf16(bv, h, lo);
            BTh[tid][s] = h; BTl[tid][s] = lo;
            bf16 kh, kl; split_bf16(kv, kh, kl);
            KTh[tid][s] = kh; KTl[tid][s] = kl;
        }
        size_t so = ((size_t)b*NCH + c)*DMODEL + tid;
        Csum[so] = C; Mu[so] = mu; Bn[so] = bn;
    }
    __syncthreads();

    const int lr = l & 15, lk = l >> 4;
    bf16x8 Ah[4], Al[4];
    #pragma unroll
    for (int it = 0; it < 4; ++it) {
        int row = w*64 + it*16 + lr;
        Ah[it] = *(const bf16x8*)&BTh[row][lk*8];
        Al[it] = *(const bf16x8*)&BTl[row][lk*8];
    }
    bf16* DMc = DM + (size_t)((size_t)b*NCH + c)*MSLOT;
    #pragma unroll
    for (int jt = 0; jt < 16; ++jt) {
        int jcol = jt*16 + lr;
        bf16x8 bh = *(const bf16x8*)&KTh[jcol][lk*8];
        bf16x8 bl = *(const bf16x8*)&KTl[jcol][lk*8];
        #pragma unroll
        for (int it = 0; it < 4; ++it) {
            f32x4 a = {0.f,0.f,0.f,0.f};
            a = MFMA(Ah[it], bh, a);
            a = MFMA(Al[it], bh, a);
            a = MFMA(Ah[it], bl, a);
            #pragma unroll
            for (int r = 0; r < 4; ++r)
                DMc[(size_t)(w*64 + it*16 + lk*4 + r)*DMODEL + jcol] = (bf16)a[r];
        }
    }
}

// ---------------- sequential compose of (m,n) boundary states (batch-4 prefetched)
__global__ __launch_bounds__(256) void chunk_compose(
    const float* __restrict__ Csum, const float* __restrict__ Mu, const float* __restrict__ Bn,
    float* __restrict__ mIn, float* __restrict__ nIn, float* __restrict__ Th,
    float* __restrict__ Dd, float* __restrict__ Ee)
{
    const int b = blockIdx.x;
    const int j = threadIdx.x;
    float m = 0.f, n = 0.f;
    #pragma unroll 1
    for (int c = 0; c < NCH; c += 4) {
        size_t o0 = ((size_t)b*NCH + c)*DMODEL + j;
        float cs0 = Csum[o0],            mu0 = Mu[o0],            bn0 = Bn[o0];
        float cs1 = Csum[o0 + DMODEL],   mu1 = Mu[o0 + DMODEL],   bn1 = Bn[o0 + DMODEL];
        float cs2 = Csum[o0 + 2*DMODEL], mu2 = Mu[o0 + 2*DMODEL], bn2 = Bn[o0 + 2*DMODEL];
        float cs3 = Csum[o0 + 3*DMODEL], mu3 = Mu[o0 + 3*DMODEL], bn3 = Bn[o0 + 3*DMODEL];
        #define STEP(CS, MUv, BNv, OFF) { \
            mIn[o0 + (OFF)] = m; nIn[o0 + (OFF)] = n; \
            float th = fmaxf(m, MUv); \
            Th[o0 + (OFF)] = th; \
            float emu = __expf(MUv - th); \
            float d = __expf(m - th); \
            Dd[o0 + (OFF)] = d; Ee[o0 + (OFF)] = emu; \
            n = d*n + emu*(BNv); \
            m = (CS) + th; }
        STEP(cs0, mu0, bn0, 0)
        STEP(cs1, mu1, bn1, DMODEL)
        STEP(cs2, mu2, bn2, 2*DMODEL)
        STEP(cs3, mu3, bn3, 3*DMODEL)
        #undef STEP
    }
}

// ---------------- compose M across chunks; 512 threads = 2 i-rows per block (1KB/step)
__global__ __launch_bounds__(512) void s3_compose(
    const float* __restrict__ Dd, const float* __restrict__ Ee, bf16* __restrict__ DM)
{
    const int b = blockIdx.x >> 7;
    const int i = ((blockIdx.x & 127) << 1) + (threadIdx.x >> 8);
    const int j = threadIdx.x & 255;
    float acc = 0.f;
    const size_t base = ((size_t)b*NCH)*MSLOT + (size_t)i*DMODEL + j;
    const size_t sb = (size_t)b*NCH*DMODEL + i;
    #pragma unroll 1
    for (int c = 0; c < NCH; c += 4) {
        float dm0 = (float)DM[base + (size_t)(c+0)*MSLOT];
        float dm1 = (float)DM[base + (size_t)(c+1)*MSLOT];
        float dm2 = (float)DM[base + (size_t)(c+2)*MSLOT];
        float dm3 = (float)DM[base + (size_t)(c+3)*MSLOT];
        float d0 = Dd[sb + (size_t)(c+0)*DMODEL], e0 = Ee[sb + (size_t)(c+0)*DMODEL];
        float d1 = Dd[sb + (size_t)(c+1)*DMODEL], e1 = Ee[sb + (size_t)(c+1)*DMODEL];
        float d2 = Dd[sb + (size_t)(c+2)*DMODEL], e2 = Ee[sb + (size_t)(c+2)*DMODEL];
        float d3 = Dd[sb + (size_t)(c+3)*DMODEL], e3 = Ee[sb + (size_t)(c+3)*DMODEL];
        if (c > 0) DM[base + (size_t)(c+0)*MSLOT] = (bf16)acc;
        acc = d0*acc + e0*dm0;
        DM[base + (size_t)(c+1)*MSLOT] = (bf16)acc;
        acc = d1*acc + e1*dm1;
        DM[base + (size_t)(c+2)*MSLOT] = (bf16)acc;
        acc = d2*acc + e2*dm2;
        DM[base + (size_t)(c+3)*MSLOT] = (bf16)acc;
        acc = d3*acc + e3*dm3;
    }
}

// ---------------- per-chunk output + fused RMSNorm (bf16 MFMA path, f16 plane inputs)
__global__ __launch_bounds__(256) void s4_chunk(
    const f16* __restrict__ qP, const f16* __restrict__ kP, const f16* __restrict__ vP,
    const f16* __restrict__ liP, const f16* __restrict__ lfP, const f16* __restrict__ soP,
    const float* __restrict__ mIn, const float* __restrict__ nIn, const float* __restrict__ Th,
    const bf16* __restrict__ DM, const float* __restrict__ norm_scale,
    float* __restrict__ out)
{
    __shared__ __align__(16) char kqbuf[33792];
    bf16 (*Kf)[264] = (bf16(*)[264])kqbuf;
    bf16 (*Qf)[264] = (bf16(*)[264])(kqbuf + 16896);
    float (*Hout)[264] = (float(*)[264])kqbuf;
    __shared__ bf16 F1L[CH_L][264];
    __shared__ __align__(16) bf16 BTh[DMODEL][40];
    __shared__ __align__(16) bf16 GT[CH_L][48];
    __shared__ float part[CH_L][4];
    __shared__ float denoms[CH_L];
    __shared__ float exL[DMODEL];

    const int tid = threadIdx.x;
    const int w = tid >> 6, l = tid & 63;
    const int b = blockIdx.x >> 6;
    const int c = blockIdx.x & 63;
    const size_t pb = ((size_t)b*T_LEN + (size_t)c*CH_L)*DMODEL;

    // phase 1: per-dim recurrences (thread = dim)
    const int i = tid;
    const size_t cbx = ((size_t)b*NCH + c)*DMODEL + i;
    const float thL = Th[cbx];
    const float mI = mIn[cbx];
    float P[CH_L];
    {
        float C = 0.f, mu = -3e38f, n = nIn[cbx], thp = mI;
        #pragma unroll
        for (int t = 0; t < CH_L; ++t) {
            size_t o = pb + (size_t)t*DMODEL + i;
            float lf = nsoftplus_fast((float)lfP[o]);
            float li = 10.0f * tanh_fast(0.1f * (float)liP[o]);
            float kv = (float)kP[o], qv = (float)qP[o], vv = (float)vP[o];
            C += lf;
            float vlc = li - C;
            mu = fmaxf(mu, vlc);
            float tht = fmaxf(mI, mu);
            float f = __expf(thp - tht);
            float iv = __expf(vlc - tht);
            n = f*n + iv*kv;
            thp = tht;
            P[t] = n * qv;
            Kf[t][i] = (bf16)kv;
            Qf[t][i] = (bf16)qv;
            F1L[t][i] = (bf16)__expf(mI - tht);
            BTh[i][t] = (bf16)(__expf(vlc - thL) * vv);
        }
        exL[i] = __expf(thL - mI);
    }
    // phase 2: wave-reduce P
    #pragma unroll
    for (int t = 0; t < CH_L; ++t) {
        float s = P[t];
        #pragma unroll
        for (int sh = 32; sh; sh >>= 1) s += __shfl_xor(s, sh);
        if (l == 0) part[t][w] = s;
    }
    __syncthreads();

    // phase 3a: denominators
    if (tid < CH_L)
        denoms[tid] = fmaxf(fabsf(part[tid][0] + part[tid][1] + part[tid][2] + part[tid][3]), 1e-6f);

    // phase 3b: G = K Q^T single-pass bf16
    {
        const int a = w & 1, bb = w >> 1;
        const int lr = l & 15, lk2 = l >> 4;
        if (a == 1 && bb == 0) {
            bf16x4 z = {(bf16)0.f, (bf16)0.f, (bf16)0.f, (bf16)0.f};
            *(bf16x4*)&GT[lr][16 + lk2*4] = z;
        } else {
            f32x4 g = {0.f,0.f,0.f,0.f};
            #pragma unroll
            for (int ks = 0; ks < 8; ++ks) {
                bf16x8 ah = *(const bf16x8*)&Kf[16*a  + lr][ks*32 + lk2*8];
                bf16x8 bh = *(const bf16x8*)&Qf[16*bb + lr][ks*32 + lk2*8];
                g = MFMA(ah, bh, g);
            }
            bf16x4 gv;
            #pragma unroll
            for (int r = 0; r < 4; ++r) {
                int s = 16*a + lk2*4 + r, t = 16*bb + lr;
                gv[r] = (s <= t) ? (bf16)g[r] : (bf16)0.f;
            }
            *(bf16x4*)&GT[16*bb + lr][16*a + lk2*4] = gv;
        }
    }
    __syncthreads();

    // phase 4: output GEMMs
    const int tt = w & 1;
    const int lr = l & 15, lk2 = l >> 4;
    const int trow = tt*16 + lr;
    f32x4 acc_a[8], acc_b[8];

    {
        bf16x8 gh = *(const bf16x8*)&GT[trow][lk2*8];
        #pragma unroll
        for (int it = 0; it < 8; ++it) {
            int irow = ((w>>1)*8 + it)*16 + lr;
            bf16x8 bb2 = *(const bf16x8*)&BTh[irow][lk2*8];
            f32x4 a = {0.f,0.f,0.f,0.f};
            acc_a[it] = MFMA(gh, bb2, a);
        }
    }
    #pragma unroll
    for (int it = 0; it < 8; ++it) acc_b[it] = (f32x4){0.f,0.f,0.f,0.f};
    if (c > 0) {
        const u16* Mbase = (const u16*)DM + (size_t)((size_t)b*NCH + c)*MSLOT;
        #pragma unroll
        for (int ks = 0; ks < 8; ++ks) {
            bf16x8 qh = *(const bf16x8*)&Qf[trow][ks*32 + lk2*8];
            #pragma unroll
            for (int it = 0; it < 8; ++it) {
                int irow = ((w>>1)*8 + it)*16 + lr;
                union { u16x8 u; bf16x8 h; } M8;
                M8.u = *(const u16x8*)(Mbase + (size_t)irow*DMODEL + ks*32 + lk2*8);
                acc_b[it] = MFMA(qh, M8.h, acc_b[it]);
            }
        }
    }
    __syncthreads();   // all Kf/Qf reads done; kqbuf becomes Hout

    // epilogue part 1
    #pragma unroll
    for (int it = 0; it < 8; ++it) {
        int icol = ((w>>1)*8 + it)*16 + lr;
        float ex = exL[icol];
        #pragma unroll
        for (int r = 0; r < 4; ++r) {
            int t = tt*16 + lk2*4 + r;
            float F1 = (float)F1L[t][icol];
            float h = F1 * (acc_b[it][r] + ex * acc_a[it][r]);
            size_t o = pb + (size_t)t*DMODEL + icol;
            Hout[t][icol] = sigmoid_fast((float)soP[o]) * h / denoms[t];
        }
    }
    __syncthreads();
    // epilogue part 2: fused RMSNorm
    #pragma unroll
    for (int r = 0; r < 8; ++r) {
        int t = w*8 + r;
        f32x4 hv = *(const f32x4*)&Hout[t][l*4];
        float ss = hv[0]*hv[0] + hv[1]*hv[1] + hv[2]*hv[2] + hv[3]*hv[3];
        #pragma unroll
        for (int sh = 32; sh; sh >>= 1) ss += __shfl_xor(ss, sh);
        float rinv = rsqrtf(ss * (1.0f/256.0f) + 1e-8f);
        f32x4 ns = *(const f32x4*)(norm_scale + l*4);
        f32x4 o4;
        #pragma unroll
        for (int e = 0; e < 4; ++e) o4[e] = hv[e] * rinv * ns[e];
        *(f32x4*)(out + pb + (size_t)t*DMODEL + l*4) = o4;
    }
}

extern "C" void kernel_launch(void* const* d_in, const int* in_sizes, int n_in,
                              void* d_out, int out_size, void* d_ws, size_t ws_size,
                              hipStream_t stream) {
    const float* x          = (const float*)d_in[0];
    const float* Wq         = (const float*)d_in[1];
    const float* bq         = (const float*)d_in[2];
    const float* Wk         = (const float*)d_in[3];
    const float* bk         = (const float*)d_in[4];
    const float* Wv         = (const float*)d_in[5];
    const float* bv         = (const float*)d_in[6];
    const float* Wg         = (const float*)d_in[7];
    const float* bg         = (const float*)d_in[8];
    const float* input_bias = (const float*)d_in[9];
    const float* norm_scale = (const float*)d_in[10];
    float* out = (float*)d_out;

    // f32 scratch
    float* Csum = (float*)d_ws;
    float* Mu   = Csum + SUMSZ;
    float* Bn   = Mu   + SUMSZ;
    float* mIn  = Bn   + SUMSZ;
    float* nIn  = mIn  + SUMSZ;
    float* Th   = nIn  + SUMSZ;
    float* Dd   = Th   + SUMSZ;
    float* Ee   = Dd   + SUMSZ;
    float* biasC = Ee  + SUMSZ;                        // 1536 floats (pad 2048)
    // f16/bf16 scratch
    f16*   qP   = (f16*)(biasC + 2048);
    f16*   kP   = qP  + PLANE;
    f16*   vP   = kP  + PLANE;
    f16*   liP  = vP  + PLANE;
    f16*   lfP  = liP + PLANE;
    f16*   soP  = lfP + PLANE;
    bf16*  DM   = (bf16*)(soP + PLANE);                // 4*64*65536 bf16 = 32 MiB
    f16*   Wf   = (f16*)(DM + (size_t)BATCH*NCH*MSLOT);
    f16*   xf   = Wf + 1536*256;

    prep<<<dim3(1120), dim3(256), 0, stream>>>(x, Wq, Wk, Wv, Wg, bq, bk, bv, bg, input_bias,
                                               xf, Wf, biasC);
    proj_gemm<<<dim3(64, 12), dim3(256), 0, stream>>>(xf, Wf, biasC,
                                                      qP, kP, vP, liP, lfP, soP);
    s2_dm<<<dim3(BATCH*NCH), dim3(256), 0, stream>>>(kP, vP, liP, lfP, Csum, Mu, Bn, DM);
    chunk_compose<<<dim3(BATCH), dim3(256), 0, stream>>>(Csum, Mu, Bn, mIn, nIn, Th, Dd, Ee);
    s3_compose<<<dim3(BATCH*128), dim3(512), 0, stream>>>(Dd, Ee, DM);
    s4_chunk<<<dim3(BATCH*NCH), dim3(256), 0, stream>>>(qP, kP, vP, liP, lfP, soP,
                                                        mIn, nIn, Th, DM, norm_scale, out);
}